// Round 2
// baseline (7038.953 us; speedup 1.0000x reference)
//
#include <hip/hip_runtime.h>
#include <hip/hip_bf16.h>
#include <cstdio>
#include <cstdint>

// Problem constants
#define BB 64
#define TT 512
#define II 512
#define HH 1024
#define G4H 4096   // 4*H
#define TC 256     // timesteps per chunk (2 chunks)

typedef __attribute__((ext_vector_type(8))) short short8b;  // 8 bf16 (4 VGPRs)
typedef __attribute__((ext_vector_type(4))) float f32x4;    // MFMA accumulator

union U16 { uint4 u; short8b s; };

__device__ __forceinline__ ushort f2bf(float f) {
    union { float f; unsigned u; } x; x.f = f;
    unsigned r = x.u + 0x7FFFu + ((x.u >> 16) & 1u);
    return (ushort)(r >> 16);
}
__device__ __forceinline__ float bf2f(ushort b) {
    union { unsigned u; float f; } x; x.u = ((unsigned)b) << 16;
    return x.f;
}
__device__ __forceinline__ float sigm(float x) { return 1.f / (1.f + __expf(-x)); }
__device__ __forceinline__ float tanh_(float x) { return 2.f / (1.f + __expf(-2.f * x)) - 1.f; }

// ---------------- prep: f32 -> bf16 convert (x) ----------------
__global__ void conv_f32_bf16(const float* __restrict__ in, ushort* __restrict__ out, int n) {
    int i = (blockIdx.x * blockDim.x + threadIdx.x) * 4;
    int stride = gridDim.x * blockDim.x * 4;
    for (; i < n; i += stride) {
        float4 v = *(const float4*)(in + i);
        ushort4 o;
        o.x = f2bf(v.x); o.y = f2bf(v.y); o.z = f2bf(v.z); o.w = f2bf(v.w);
        *(ushort4*)(out + i) = o;
    }
}

// ---------------- prep: transpose f32 [K][1024] -> bf16 [1024][K] ----------------
__global__ void transpose_bf16(const float* __restrict__ in, ushort* __restrict__ out, int K) {
    __shared__ float tile[32][33];
    int j0 = blockIdx.x * 32;   // col of in / row of out
    int k0 = blockIdx.y * 32;   // row of in / col of out
    int tx = threadIdx.x, ty = threadIdx.y;  // 32 x 8
    #pragma unroll
    for (int i = 0; i < 32; i += 8)
        tile[ty + i][tx] = in[(size_t)(k0 + ty + i) * 1024 + j0 + tx];
    __syncthreads();
    #pragma unroll
    for (int i = 0; i < 32; i += 8)
        out[(size_t)(j0 + ty + i) * K + k0 + tx] = f2bf(tile[tx][ty + i]);
}

// ---------------- phase A: xU(chunk) = x(:, t0:t0+TC, :) @ [U_ig|U_f|U_c|U_o] + b ----
// A = x_bf16 [64][512][512] (row remap per chunk); Bt = U_t [4096][512]; C = xU [B*TC][4096] bf16
__global__ __launch_bounds__(256) void gemm_xu(
    const ushort* __restrict__ A, const ushort* __restrict__ Bt,
    const float* __restrict__ b0, const float* __restrict__ b1,
    const float* __restrict__ b2, const float* __restrict__ b3,
    ushort* __restrict__ C, int t0)
{
    __shared__ ushort As[128 * 64];  // [row][k] bf16, XOR-swizzled
    __shared__ ushort Bs[128 * 64];  // [col][k] bf16, XOR-swizzled
    const int m0 = blockIdx.x * 128;           // chunk-local row base (0..16383)
    const int n0 = blockIdx.y * 128;
    const int tid = threadIdx.x;
    const int lane = tid & 63;
    const int wave = tid >> 6;          // 0..3
    const int wm = (wave >> 1) * 64;    // 0 or 64
    const int wn = (wave & 1) * 64;     // 0 or 64
    const int kgrp = lane >> 4;         // 0..3

    // row remap: chunk row r -> x row = b*512 + t0 + tloc ; b = m0>>8 const per block
    const ushort* Abase = A + ((size_t)(m0 >> 8) * TT + t0 + (m0 & 255)) * 512;

    f32x4 acc[4][4];
    #pragma unroll
    for (int i = 0; i < 4; ++i)
        #pragma unroll
        for (int j = 0; j < 4; ++j) acc[i][j] = (f32x4){0.f, 0.f, 0.f, 0.f};

    for (int k0 = 0; k0 < 512; k0 += 64) {
        __syncthreads();
        #pragma unroll
        for (int p = 0; p < 4; ++p) {
            int idx = p * 256 + tid;   // 0..1023
            int row = idx >> 3;        // 0..127
            int kc  = idx & 7;         // 8-elem chunk
            uint4 va = *(const uint4*)(Abase + (size_t)row * 512 + k0 + kc * 8);
            uint4 vb = *(const uint4*)(Bt + (size_t)(n0 + row) * 512 + k0 + kc * 8);
            int bo = (row * 128 + kc * 16) ^ ((row & 7) << 4);
            *(uint4*)((char*)As + bo) = va;
            *(uint4*)((char*)Bs + bo) = vb;
        }
        __syncthreads();
        #pragma unroll
        for (int ks = 0; ks < 2; ++ks) {
            U16 af[4], bfr[4];
            #pragma unroll
            for (int i = 0; i < 4; ++i) {
                int row = wm + i * 16 + (lane & 15);
                int ao = (row * 128 + ks * 64 + kgrp * 16) ^ ((row & 7) << 4);
                af[i].u = *(const uint4*)((const char*)As + ao);
                int col = wn + i * 16 + (lane & 15);
                int bo = (col * 128 + ks * 64 + kgrp * 16) ^ ((col & 7) << 4);
                bfr[i].u = *(const uint4*)((const char*)Bs + bo);
            }
            #pragma unroll
            for (int i = 0; i < 4; ++i)
                #pragma unroll
                for (int j = 0; j < 4; ++j)
                    acc[i][j] = __builtin_amdgcn_mfma_f32_16x16x32_bf16(af[i].s, bfr[j].s, acc[i][j], 0, 0, 0);
        }
    }
    // epilogue: + bias, -> bf16
    #pragma unroll
    for (int i = 0; i < 4; ++i) {
        #pragma unroll
        for (int j = 0; j < 4; ++j) {
            int row = m0 + wm + i * 16 + (lane >> 4) * 4;
            int col = n0 + wn + j * 16 + (lane & 15);
            int gate = col >> 10;
            const float* bp = (gate == 0) ? b0 : (gate == 1) ? b1 : (gate == 2) ? b2 : b3;
            float bias = bp[col & 1023];
            #pragma unroll
            for (int r = 0; r < 4; ++r)
                C[(size_t)(row + r) * G4H + col] = f2bf(acc[i][j][r] + bias);
        }
    }
}

// ---------------- phase B: persistent recurrent kernel ----------------
// 256 WGs x 256 threads = 4 batch groups (16 rows) x 64 hidden slices (16 h-cols = 64 V-cols).
// Groups are independent recurrences (batch-parallel); barrier = 64 flags per group.
// h layout (blocked, avoids cross-XCD false sharing): hbuf[parity][slice][64 rows][16]
__global__ __launch_bounds__(256) void lstm_rec(
    const ushort* __restrict__ xU,   // [B*TC][4096] bf16 chunk, row = b*TC + (t-t0)
    const ushort* __restrict__ V_t,  // [4096][1024] bf16 (V transposed)
    ushort* __restrict__ hbuf,       // [2][64][64][16] bf16
    float* __restrict__ cbuf,        // [64][1024] f32 (c carried across chunks)
    float* __restrict__ out,         // h[64*1024] then c[64*1024], f32
    unsigned* __restrict__ flags,    // [4][64]
    int t0)
{
    __shared__ ushort Vl[64 * 1024];   // [c][k] XOR-swizzled; 128 KB
    __shared__ float g_lds[16][64];    // 4 KB
    const int wgid = blockIdx.x;
    const int grp = wgid >> 6;        // batch group: rows grp*16..+16
    const int slice = wgid & 63;      // h-col slice: cols slice*16..+16
    const int tid = threadIdx.x;
    const int lane = tid & 63;
    const int gate = tid >> 6;        // wave = gate 0..3

    // ---- stage V slice: LDS col c = gate*16 + jh -> V_t row (c>>4)*1024 + slice*16 + (c&15)
    #pragma unroll
    for (int p = 0; p < 32; ++p) {
        int idx = p * 256 + tid;  // 0..8191
        int c  = idx >> 7;        // 0..63
        int kc = idx & 127;       // 8-elem k chunk
        int colg = (c >> 4) * 1024 + slice * 16 + (c & 15);
        uint4 v = *(const uint4*)(V_t + (size_t)colg * 1024 + kc * 8);
        int bo = (c * 2048 + kc * 16) ^ ((c & 7) << 4);
        *(uint4*)((char*)Vl + bo) = v;
    }

    const int bb = tid >> 4, jh = tid & 15;    // epilogue thread -> (row-in-grp, h-col-in-slice)
    const int hcol = slice * 16 + jh;
    const int growf = grp * 16 + bb;           // global batch row for this thread
    float c_reg;
    unsigned* myflag = flags + grp * 64 + slice;

    if (t0 == 0) {
        // zero our region of h buffer 0 and init c
        hbuf[(size_t)slice * 1024 + growf * 16 + jh] = 0;
        c_reg = 0.f;
        __syncthreads();
        if (tid == 0)
            __hip_atomic_store(myflag, 1u, __ATOMIC_RELEASE, __HIP_MEMORY_SCOPE_AGENT);
    } else {
        c_reg = cbuf[(size_t)growf * 1024 + hcol];
        __syncthreads();  // V staged
    }

    // MFMA fragment constants
    const int arow = grp * 16 + (lane & 15);  // h row for A frag
    const int kgrp = lane >> 4;               // 0..3
    const int bc = gate * 16 + (lane & 15);   // LDS col for B frag
    const int bxor = (bc & 7) << 4;
    const int bo_base = bc * 2048 + kgrp * 16;
    // A frag addr within blocked h: block = ks*2 + (kgrp>>1), elem off (kgrp&1)*8
    const size_t a_off = (size_t)(kgrp >> 1) * 1024 + (size_t)arow * 16 + (kgrp & 1) * 8;

    for (int t = t0; t < t0 + TC; ++t) {
        // prefetch xU operands (independent of the flag barrier)
        size_t xbase = ((size_t)growf * TC + (t - t0)) * G4H + hcol;
        ushort xi = xU[xbase], xf = xU[xbase + 1024], xc = xU[xbase + 2048], xo = xU[xbase + 3072];

        // ---- wait for all 64 producers of this group's h_t
        if (gate == 0) {
            unsigned tgt = (unsigned)(t + 1);
            const unsigned* f = flags + grp * 64;
            while (true) {
                unsigned v = __hip_atomic_load(&f[lane], __ATOMIC_RELAXED, __HIP_MEMORY_SCOPE_AGENT);
                if (__all(v >= tgt)) break;
                __builtin_amdgcn_s_sleep(1);
            }
            __threadfence();  // acquire: invalidate caches before reading h
        }
        __syncthreads();

        // ---- h_t @ V slice  (16 x 64 output, K=1024) : wave `gate` does 16x16 cols
        const ushort* hsrc = hbuf + (size_t)(t & 1) * 65536;
        const ushort* aptr = hsrc + a_off;
        f32x4 acc0 = (f32x4){0.f,0.f,0.f,0.f}, acc1 = (f32x4){0.f,0.f,0.f,0.f};
        #pragma unroll
        for (int ks = 0; ks < 32; ks += 2) {
            U16 a, b;
            a.u = *(const uint4*)(aptr + (size_t)ks * 2048);
            b.u = *(const uint4*)((const char*)Vl + ((bo_base + ks * 64) ^ bxor));
            acc0 = __builtin_amdgcn_mfma_f32_16x16x32_bf16(a.s, b.s, acc0, 0, 0, 0);
            a.u = *(const uint4*)(aptr + (size_t)ks * 2048 + 2048);
            b.u = *(const uint4*)((const char*)Vl + ((bo_base + ks * 64 + 64) ^ bxor));
            acc1 = __builtin_amdgcn_mfma_f32_16x16x32_bf16(a.s, b.s, acc1, 0, 0, 0);
        }
        acc0 += acc1;
        // scatter: row = (lane>>4)*4 + r, col = gate*16 + (lane&15)
        {
            int rb = (lane >> 4) * 4, col = gate * 16 + (lane & 15);
            #pragma unroll
            for (int r = 0; r < 4; ++r) g_lds[rb + r][col] = acc0[r];
        }
        __syncthreads();

        // ---- gates + state update (thread (bb, jh))
        {
            float gi = g_lds[bb][jh]      + bf2f(xi);
            float gf = g_lds[bb][16 + jh] + bf2f(xf);
            float gc = g_lds[bb][32 + jh] + bf2f(xc);
            float go = g_lds[bb][48 + jh] + bf2f(xo);
            float ig = sigm(gi), fg = sigm(gf), ct = tanh_(gc), og = sigm(go);
            c_reg = ig * ct + fg * c_reg;
            float h = og * tanh_(c_reg);
            ushort* hdst = hbuf + (size_t)((t & 1) ^ 1) * 65536;
            hdst[(size_t)slice * 1024 + growf * 16 + jh] = f2bf(h);
            if (t == TT - 1) {
                out[(size_t)growf * 1024 + hcol] = h;
                out[(size_t)BB * HH + (size_t)growf * 1024 + hcol] = c_reg;
            }
        }
        __syncthreads();
        if (tid == 0)
            __hip_atomic_store(myflag, (unsigned)(t + 2), __ATOMIC_RELEASE, __HIP_MEMORY_SCOPE_AGENT);
    }

    if (t0 + TC < TT)
        cbuf[(size_t)growf * 1024 + hcol] = c_reg;
}

// ---------------- host ----------------
extern "C" void kernel_launch(void* const* d_in, const int* in_sizes, int n_in,
                              void* d_out, int out_size, void* d_ws, size_t ws_size,
                              hipStream_t stream) {
    const float* x = (const float*)d_in[0];
    const float* U[4] = {(const float*)d_in[1], (const float*)d_in[4], (const float*)d_in[7], (const float*)d_in[10]};
    const float* V[4] = {(const float*)d_in[2], (const float*)d_in[5], (const float*)d_in[8], (const float*)d_in[11]};
    const float* bias[4] = {(const float*)d_in[3], (const float*)d_in[6], (const float*)d_in[9], (const float*)d_in[12]};
    float* out = (float*)d_out;

    // workspace layout (~181 MB)
    const size_t x_elems = (size_t)BB * TT * II;
    size_t off = 0;
    auto alloc = [&](size_t bytes) { size_t o = off; off = (off + bytes + 255) & ~(size_t)255; return o; };
    size_t o_xbf   = alloc(x_elems * 2);                  // 32 MB
    size_t o_Ut    = alloc((size_t)G4H * II * 2);         // 4 MB
    size_t o_Vt    = alloc((size_t)G4H * HH * 2);         // 8 MB
    size_t o_xU    = alloc((size_t)BB * TC * G4H * 2);    // 128 MB (per-chunk)
    size_t o_hbuf  = alloc((size_t)2 * BB * HH * 2);      // 256 KB
    size_t o_cbuf  = alloc((size_t)BB * HH * 4);          // 256 KB
    size_t o_flags = alloc(4 * 64 * 4);
    if (ws_size < off) {
        fprintf(stderr, "kernel_launch: ws too small: need %zu have %zu\n", off, ws_size);
        return;
    }
    char* ws = (char*)d_ws;
    ushort* x_bf = (ushort*)(ws + o_xbf);
    ushort* U_t  = (ushort*)(ws + o_Ut);
    ushort* V_t  = (ushort*)(ws + o_Vt);
    ushort* xU   = (ushort*)(ws + o_xU);
    ushort* hbuf = (ushort*)(ws + o_hbuf);
    float*  cbuf = (float*)(ws + o_cbuf);
    unsigned* flags = (unsigned*)(ws + o_flags);

    hipMemsetAsync(flags, 0, 4 * 64 * 4, stream);

    conv_f32_bf16<<<4096, 256, 0, stream>>>(x, x_bf, (int)x_elems);

    for (int g = 0; g < 4; ++g)
        transpose_bf16<<<dim3(32, 16), dim3(32, 8), 0, stream>>>(U[g], U_t + (size_t)g * 1024 * 512, 512);
    for (int g = 0; g < 4; ++g)
        transpose_bf16<<<dim3(32, 32), dim3(32, 8), 0, stream>>>(V[g], V_t + (size_t)g * 1024 * 1024, 1024);

    for (int c = 0; c < TT / TC; ++c) {
        int t0 = c * TC;
        gemm_xu<<<dim3(128, 32), 256, 0, stream>>>(x_bf, U_t, bias[0], bias[1], bias[2], bias[3], xU, t0);
        lstm_rec<<<256, 256, 0, stream>>>(xU, V_t, hbuf, cbuf, out, flags, t0);
    }
}

// Round 3
// 2108.778 us; speedup vs baseline: 3.3379x; 3.3379x over previous
//
#include <hip/hip_runtime.h>
#include <hip/hip_bf16.h>
#include <cstdio>
#include <cstdint>

// Problem constants
#define BB 64
#define TT 512
#define II 512
#define HH 1024
#define G4H 4096   // 4*H
#define TC 256     // timesteps per chunk (2 chunks)

typedef __attribute__((ext_vector_type(8))) short short8b;  // 8 bf16 (4 VGPRs)
typedef __attribute__((ext_vector_type(4))) float f32x4;    // MFMA accumulator

union U16 { uint4 u; short8b s; };

#define AT_LD32(p)   __hip_atomic_load((p), __ATOMIC_RELAXED, __HIP_MEMORY_SCOPE_AGENT)
#define AT_LD64(p)   __hip_atomic_load((p), __ATOMIC_RELAXED, __HIP_MEMORY_SCOPE_AGENT)
#define AT_ST32(p,v) __hip_atomic_store((p), (v), __ATOMIC_RELAXED, __HIP_MEMORY_SCOPE_AGENT)
#define AT_ST64(p,v) __hip_atomic_store((p), (v), __ATOMIC_RELAXED, __HIP_MEMORY_SCOPE_AGENT)

__device__ __forceinline__ ushort f2bf(float f) {
    union { float f; unsigned u; } x; x.f = f;
    unsigned r = x.u + 0x7FFFu + ((x.u >> 16) & 1u);
    return (ushort)(r >> 16);
}
__device__ __forceinline__ float bf2f(ushort b) {
    union { unsigned u; float f; } x; x.u = ((unsigned)b) << 16;
    return x.f;
}
__device__ __forceinline__ float sigm(float x) { return 1.f / (1.f + __expf(-x)); }
__device__ __forceinline__ float tanh_(float x) { return 2.f / (1.f + __expf(-2.f * x)) - 1.f; }

// ---------------- prep: f32 -> bf16 convert (x) ----------------
__global__ void conv_f32_bf16(const float* __restrict__ in, ushort* __restrict__ out, int n) {
    int i = (blockIdx.x * blockDim.x + threadIdx.x) * 4;
    int stride = gridDim.x * blockDim.x * 4;
    for (; i < n; i += stride) {
        float4 v = *(const float4*)(in + i);
        ushort4 o;
        o.x = f2bf(v.x); o.y = f2bf(v.y); o.z = f2bf(v.z); o.w = f2bf(v.w);
        *(ushort4*)(out + i) = o;
    }
}

// ---------------- prep: transpose f32 [K][1024] -> bf16 [1024][K] ----------------
__global__ void transpose_bf16(const float* __restrict__ in, ushort* __restrict__ out, int K) {
    __shared__ float tile[32][33];
    int j0 = blockIdx.x * 32;
    int k0 = blockIdx.y * 32;
    int tx = threadIdx.x, ty = threadIdx.y;  // 32 x 8
    #pragma unroll
    for (int i = 0; i < 32; i += 8)
        tile[ty + i][tx] = in[(size_t)(k0 + ty + i) * 1024 + j0 + tx];
    __syncthreads();
    #pragma unroll
    for (int i = 0; i < 32; i += 8)
        out[(size_t)(j0 + ty + i) * K + k0 + tx] = f2bf(tile[tx][ty + i]);
}

// ---------------- phase A: xU(chunk) = x(:, t0:t0+TC, :) @ [U_ig|U_f|U_c|U_o] + b ----
__global__ __launch_bounds__(256) void gemm_xu(
    const ushort* __restrict__ A, const ushort* __restrict__ Bt,
    const float* __restrict__ b0, const float* __restrict__ b1,
    const float* __restrict__ b2, const float* __restrict__ b3,
    ushort* __restrict__ C, int t0)
{
    __shared__ ushort As[128 * 64];
    __shared__ ushort Bs[128 * 64];
    const int m0 = blockIdx.x * 128;
    const int n0 = blockIdx.y * 128;
    const int tid = threadIdx.x;
    const int lane = tid & 63;
    const int wave = tid >> 6;
    const int wm = (wave >> 1) * 64;
    const int wn = (wave & 1) * 64;
    const int kgrp = lane >> 4;

    const ushort* Abase = A + ((size_t)(m0 >> 8) * TT + t0 + (m0 & 255)) * 512;

    f32x4 acc[4][4];
    #pragma unroll
    for (int i = 0; i < 4; ++i)
        #pragma unroll
        for (int j = 0; j < 4; ++j) acc[i][j] = (f32x4){0.f, 0.f, 0.f, 0.f};

    for (int k0 = 0; k0 < 512; k0 += 64) {
        __syncthreads();
        #pragma unroll
        for (int p = 0; p < 4; ++p) {
            int idx = p * 256 + tid;
            int row = idx >> 3;
            int kc  = idx & 7;
            uint4 va = *(const uint4*)(Abase + (size_t)row * 512 + k0 + kc * 8);
            uint4 vb = *(const uint4*)(Bt + (size_t)(n0 + row) * 512 + k0 + kc * 8);
            int bo = (row * 128 + kc * 16) ^ ((row & 7) << 4);
            *(uint4*)((char*)As + bo) = va;
            *(uint4*)((char*)Bs + bo) = vb;
        }
        __syncthreads();
        #pragma unroll
        for (int ks = 0; ks < 2; ++ks) {
            U16 af[4], bfr[4];
            #pragma unroll
            for (int i = 0; i < 4; ++i) {
                int row = wm + i * 16 + (lane & 15);
                int ao = (row * 128 + ks * 64 + kgrp * 16) ^ ((row & 7) << 4);
                af[i].u = *(const uint4*)((const char*)As + ao);
                int col = wn + i * 16 + (lane & 15);
                int bo = (col * 128 + ks * 64 + kgrp * 16) ^ ((col & 7) << 4);
                bfr[i].u = *(const uint4*)((const char*)Bs + bo);
            }
            #pragma unroll
            for (int i = 0; i < 4; ++i)
                #pragma unroll
                for (int j = 0; j < 4; ++j)
                    acc[i][j] = __builtin_amdgcn_mfma_f32_16x16x32_bf16(af[i].s, bfr[j].s, acc[i][j], 0, 0, 0);
        }
    }
    #pragma unroll
    for (int i = 0; i < 4; ++i) {
        #pragma unroll
        for (int j = 0; j < 4; ++j) {
            int row = m0 + wm + i * 16 + (lane >> 4) * 4;
            int col = n0 + wn + j * 16 + (lane & 15);
            int gate = col >> 10;
            const float* bp = (gate == 0) ? b0 : (gate == 1) ? b1 : (gate == 2) ? b2 : b3;
            float bias = bp[col & 1023];
            #pragma unroll
            for (int r = 0; r < 4; ++r)
                C[(size_t)(row + r) * G4H + col] = f2bf(acc[i][j][r] + bias);
        }
    }
}

// ---------------- phase B: persistent recurrent kernel ----------------
// 256 WGs x 256 threads = 4 batch groups (16 rows) x 64 hidden slices.
// V slice (1024x64) resident in LDS. All cross-WG h/flag traffic via relaxed
// agent-scope atomics (sc1 -> MALL coherence point) -- NO release/acquire
// fences (no buffer_wbl2 / buffer_inv) in the steady-state loop.
// hbuf layout: [parity][slice][64 rows][16 cols] bf16 (byte: p*131072 + slice*2048 + row*32 + jh*2)
__global__ __launch_bounds__(256) void lstm_rec(
    const ushort* __restrict__ xU,   // [B*TC][4096] bf16 chunk
    const ushort* __restrict__ V_t,  // [4096][1024] bf16 (V transposed)
    ushort* __restrict__ hbuf,       // [2][64][64][16] bf16
    float* __restrict__ cbuf,        // [64][1024] f32
    float* __restrict__ out,         // h then c, f32
    unsigned* __restrict__ flags,    // [4][64] monotonic step counters
    int t0)
{
    __shared__ __align__(16) ushort Vl[64 * 1024];  // 128 KB [col][k] XOR-swizzled
    __shared__ __align__(16) ushort hl[16 * 1024];  // 32 KB h tile [row][k] XOR-swizzled
    float* g_lds = (float*)hl;                      // overlay (first 4 KB) after MFMA reads
    char* hb = (char*)hbuf;

    const int wgid = blockIdx.x;
    const int grp = wgid >> 6;        // batch group: rows grp*16..+16
    const int slice = wgid & 63;      // h-col slice: cols slice*16..+16
    const int tid = threadIdx.x;
    const int lane = tid & 63;
    const int gate = tid >> 6;        // wave = gate 0..3

    // ---- stage V slice into LDS
    #pragma unroll
    for (int p = 0; p < 32; ++p) {
        int idx = p * 256 + tid;  // 0..8191
        int c  = idx >> 7;        // 0..63
        int kc = idx & 127;       // 8-elem k chunk
        int colg = (c >> 4) * 1024 + slice * 16 + (c & 15);
        uint4 v = *(const uint4*)(V_t + (size_t)colg * 1024 + kc * 8);
        int bo = (c * 2048 + kc * 16) ^ ((c & 7) << 4);
        *(uint4*)((char*)Vl + bo) = v;
    }

    const int bb = tid >> 4, jh = tid & 15;
    const int hcol = slice * 16 + jh;
    const int growf = grp * 16 + bb;
    float c_reg;
    unsigned* myflag = flags + grp * 64 + slice;

    if (t0 == 0) {
        // zero h parity-0 region (agent atomics so it's at MALL), init c
        if (tid < 64) {
            int b0 = tid >> 2, part = tid & 3;
            AT_ST64((unsigned long long*)(hb + slice * 2048 + (grp * 16 + b0) * 32 + part * 8), 0ull);
        }
        c_reg = 0.f;
        __syncthreads();   // drains vmcnt -> zeros visible at MALL
        if (tid == 0) AT_ST32(myflag, 1u);
    } else {
        c_reg = cbuf[(size_t)growf * 1024 + hcol];
        __syncthreads();   // Vl staged
    }

    // MFMA fragment constants
    const int kgrp = lane >> 4;               // 0..3
    const int lrow = lane & 15;               // A row within group
    const int arow_sw = (lrow & 7) << 4;
    const int bc = gate * 16 + (lane & 15);   // Vl col for B frag
    const int bxor = (bc & 7) << 4;
    const int bo_base = bc * 2048 + kgrp * 16;

    for (int t = t0; t < t0 + TC; ++t) {
        // prefetch xU operands
        size_t xbase = ((size_t)growf * TC + (t - t0)) * G4H + hcol;
        ushort xi = xU[xbase], xf = xU[xbase + 1024], xc = xU[xbase + 2048], xo = xU[xbase + 3072];

        // ---- wave 0 polls the 64 producer flags of this group (relaxed, MALL)
        if (tid < 64) {
            unsigned tgt = (unsigned)(t + 1);
            const unsigned* f = flags + grp * 64;
            while (!__all((int)(AT_LD32(&f[tid]) >= tgt)))
                __builtin_amdgcn_s_sleep(1);
            asm volatile("" ::: "memory");
        }
        __syncthreads();  // B1 (also: prev iter g_lds reads done before hl overwrite)

        // ---- stage h_t (16 rows x 1024) from MALL into LDS; all loads in flight first
        {
            const char* hsrc = hb + (size_t)(t & 1) * 131072;
            unsigned long long vv[16];
            #pragma unroll
            for (int it = 0; it < 16; ++it) {
                int q = it * 256 + tid;
                int row = q & 15, kq = q >> 4;   // kq 0..255 (k quad)
                vv[it] = AT_LD64((unsigned long long*)(hsrc + (kq >> 2) * 2048 + (grp * 16 + row) * 32 + (kq & 3) * 8));
            }
            #pragma unroll
            for (int it = 0; it < 16; ++it) {
                int q = it * 256 + tid;
                int row = q & 15, kq = q >> 4;
                int k0 = kq * 4;
                int lb = (row * 2048 + (k0 >> 3) * 16 + (k0 & 4) * 2) ^ ((row & 7) << 4);
                *(unsigned long long*)((char*)hl + lb) = vv[it];
            }
        }
        __syncthreads();  // B2

        // ---- h_t @ V slice: wave `gate` computes 16 rows x 16 cols, K=1024
        f32x4 acc0 = (f32x4){0.f,0.f,0.f,0.f}, acc1 = (f32x4){0.f,0.f,0.f,0.f};
        const char* hlb = (const char*)hl;
        #pragma unroll
        for (int ks = 0; ks < 32; ks += 2) {
            U16 a0, b0, a1, b1;
            a0.u = *(const uint4*)(hlb + ((lrow * 2048 + (ks * 4 + kgrp) * 16) ^ arow_sw));
            b0.u = *(const uint4*)((const char*)Vl + ((bo_base + ks * 64) ^ bxor));
            acc0 = __builtin_amdgcn_mfma_f32_16x16x32_bf16(a0.s, b0.s, acc0, 0, 0, 0);
            a1.u = *(const uint4*)(hlb + ((lrow * 2048 + (ks * 4 + 4 + kgrp) * 16) ^ arow_sw));
            b1.u = *(const uint4*)((const char*)Vl + ((bo_base + ks * 64 + 64) ^ bxor));
            acc1 = __builtin_amdgcn_mfma_f32_16x16x32_bf16(a1.s, b1.s, acc1, 0, 0, 0);
        }
        acc0 += acc1;
        __syncthreads();  // B3: all hl reads done (g_lds overlays hl)

        // scatter: row = (lane>>4)*4 + r, col = gate*16 + (lane&15)
        {
            int rb = (lane >> 4) * 4, col = gate * 16 + (lane & 15);
            #pragma unroll
            for (int r = 0; r < 4; ++r) g_lds[(rb + r) * 64 + col] = acc0[r];
        }
        __syncthreads();  // B4

        // ---- gates + state update (thread (bb, jh))
        {
            float gi = g_lds[bb * 64 + jh]      + bf2f(xi);
            float gf = g_lds[bb * 64 + 16 + jh] + bf2f(xf);
            float gc = g_lds[bb * 64 + 32 + jh] + bf2f(xc);
            float go = g_lds[bb * 64 + 48 + jh] + bf2f(xo);
            float ig = sigm(gi), fg = sigm(gf), ct = tanh_(gc), og = sigm(go);
            c_reg = ig * ct + fg * c_reg;
            float h = og * tanh_(c_reg);
            ushort hbf = f2bf(h);
            unsigned nb = __shfl_down((unsigned)hbf, 1);
            if (!(jh & 1)) {
                unsigned pk = (unsigned)hbf | (nb << 16);
                AT_ST32((unsigned*)(hb + (size_t)((t & 1) ^ 1) * 131072 + slice * 2048 + growf * 32 + jh * 2), pk);
            }
            if (t == TT - 1) {
                out[(size_t)growf * 1024 + hcol] = h;
                out[(size_t)BB * HH + (size_t)growf * 1024 + hcol] = c_reg;
            }
        }
        __syncthreads();  // B5: all waves' h stores drained (vmcnt) -> at MALL
        if (tid == 0) AT_ST32(myflag, (unsigned)(t + 2));
    }

    if (t0 + TC < TT)
        cbuf[(size_t)growf * 1024 + hcol] = c_reg;
}

// ---------------- host ----------------
extern "C" void kernel_launch(void* const* d_in, const int* in_sizes, int n_in,
                              void* d_out, int out_size, void* d_ws, size_t ws_size,
                              hipStream_t stream) {
    const float* x = (const float*)d_in[0];
    const float* U[4] = {(const float*)d_in[1], (const float*)d_in[4], (const float*)d_in[7], (const float*)d_in[10]};
    const float* V[4] = {(const float*)d_in[2], (const float*)d_in[5], (const float*)d_in[8], (const float*)d_in[11]};
    const float* bias[4] = {(const float*)d_in[3], (const float*)d_in[6], (const float*)d_in[9], (const float*)d_in[12]};
    float* out = (float*)d_out;

    const size_t x_elems = (size_t)BB * TT * II;
    size_t off = 0;
    auto alloc = [&](size_t bytes) { size_t o = off; off = (off + bytes + 255) & ~(size_t)255; return o; };
    size_t o_xbf   = alloc(x_elems * 2);
    size_t o_Ut    = alloc((size_t)G4H * II * 2);
    size_t o_Vt    = alloc((size_t)G4H * HH * 2);
    size_t o_xU    = alloc((size_t)BB * TC * G4H * 2);
    size_t o_hbuf  = alloc((size_t)2 * BB * HH * 2);
    size_t o_cbuf  = alloc((size_t)BB * HH * 4);
    size_t o_flags = alloc(4 * 64 * 4);
    if (ws_size < off) {
        fprintf(stderr, "kernel_launch: ws too small: need %zu have %zu\n", off, ws_size);
        return;
    }
    char* ws = (char*)d_ws;
    ushort* x_bf = (ushort*)(ws + o_xbf);
    ushort* U_t  = (ushort*)(ws + o_Ut);
    ushort* V_t  = (ushort*)(ws + o_Vt);
    ushort* xU   = (ushort*)(ws + o_xU);
    ushort* hbuf = (ushort*)(ws + o_hbuf);
    float*  cbuf = (float*)(ws + o_cbuf);
    unsigned* flags = (unsigned*)(ws + o_flags);

    hipMemsetAsync(flags, 0, 4 * 64 * 4, stream);

    conv_f32_bf16<<<4096, 256, 0, stream>>>(x, x_bf, (int)x_elems);

    for (int g = 0; g < 4; ++g)
        transpose_bf16<<<dim3(32, 16), dim3(32, 8), 0, stream>>>(U[g], U_t + (size_t)g * 1024 * 512, 512);
    for (int g = 0; g < 4; ++g)
        transpose_bf16<<<dim3(32, 32), dim3(32, 8), 0, stream>>>(V[g], V_t + (size_t)g * 1024 * 1024, 1024);

    for (int c = 0; c < TT / TC; ++c) {
        int t0 = c * TC;
        gemm_xu<<<dim3(128, 32), 256, 0, stream>>>(x_bf, U_t, bias[0], bias[1], bias[2], bias[3], xU, t0);
        lstm_rec<<<256, 256, 0, stream>>>(xU, V_t, hbuf, cbuf, out, flags, t0);
    }
}